// Round 8
// baseline (860.792 us; speedup 1.0000x reference)
//
#include <hip/hip_runtime.h>
#include <hip/hip_bf16.h>
#include <stdint.h>

// R14: fused kernels restructured for staging/compute overlap with ONLY
// __syncthreads(): per tile, stage-issues are placed right AFTER the barrier
// that frees their buffer and BEFORE a compute phase, so the vmcnt(0) drain
// at the next barrier lands after ~32 MFMA of overlap. m=64 tiles (R12's
// verified layout, 2x compute density of R13), single-buffered b1/b2 -> 73KB
// LDS -> 2 blocks/CU. MODE1 splits the n-loop 2-way (grid 512 = 2/CU) and
// writes raw PV slabs + partial rsums; reduce_pv (R9-verified) combines.
// MODE0 double-buffers b1. MODE2 m=64 unsplit (grid 512 = 2/CU).

#define B_ 8
#define N_ 4096
#define E_ 2048
#define D_ 256

typedef short bf16x8 __attribute__((ext_vector_type(8)));
typedef float f32x4 __attribute__((ext_vector_type(4)));
typedef unsigned short us8 __attribute__((ext_vector_type(8)));

#define AS1 __attribute__((address_space(1)))
#define AS3 __attribute__((address_space(3)))

__device__ __forceinline__ unsigned short f2bf(float f) {
    union { float f; unsigned int u; } v; v.f = f;
    unsigned int r = v.u + 0x7fffu + ((v.u >> 16) & 1u);
    return (unsigned short)(r >> 16);
}
__device__ __forceinline__ float bf2f(unsigned short h) {
    union { unsigned int u; float f; } v; v.u = ((unsigned int)h) << 16;
    return v.f;
}
__device__ __forceinline__ float waveReduceSum(float v) {
#pragma unroll
    for (int o = 32; o > 0; o >>= 1) v += __shfl_xor(v, o, 64);
    return v;
}

// ---------------- LayerNorm over D=256 -> bf16 ------------------------------
__global__ __launch_bounds__(256) void ln_kernel(const float* __restrict__ x,
                                                 const float* __restrict__ gamma,
                                                 const float* __restrict__ beta,
                                                 unsigned short* __restrict__ yb) {
    __shared__ float red[8];
    const int row = blockIdx.x;
    const int t = threadIdx.x;
    const int lane = t & 63, wid = t >> 6;
    const float v = x[(size_t)row * D_ + t];
    float s = waveReduceSum(v);
    if (lane == 0) red[wid] = s;
    __syncthreads();
    const float mu = (red[0] + red[1] + red[2] + red[3]) * (1.0f / D_);
    const float d = v - mu;
    float s2 = waveReduceSum(d * d);
    if (lane == 0) red[4 + wid] = s2;
    __syncthreads();
    const float var = (red[4] + red[5] + red[6] + red[7]) * (1.0f / D_);
    yb[(size_t)row * D_ + t] = f2bf(gamma[t] * d * rsqrtf(var + 1e-5f) + beta[t]);
}

// ---------------- pack ht -> bitmask: bits[b][e][n>>5] bit (n&31) -----------
__global__ __launch_bounds__(256) void pack_mask(const int* __restrict__ ht,
                                                 uint32_t* __restrict__ bits) {
    __shared__ __align__(8) unsigned char nib[256];
    const int row = blockIdx.x;
    const int t = threadIdx.x;
    const int* hrow = ht + (size_t)row * N_;
    uint32_t* brow = bits + (size_t)row * (N_ / 32);
#pragma unroll
    for (int it = 0; it < 4; ++it) {
        const int4 v = *(const int4*)&hrow[it * 1024 + t * 4];
        unsigned char n = (unsigned char)((v.x > 0) | ((v.y > 0) << 1) |
                                          ((v.z > 0) << 2) | ((v.w > 0) << 3));
        nib[t] = n;
        __syncthreads();
        if (t < 32) {
            uint64_t x = *(const uint64_t*)&nib[t * 8];
            x = (x | (x >> 4)) & 0x00FF00FF00FF00FFull;
            x = (x | (x >> 8)) & 0x0000FFFF0000FFFFull;
            brow[it * 32 + t] = (uint32_t)(x | (x >> 16));
        }
        __syncthreads();
    }
}

// ---------------- fp32 [N,D] -> bf16 [N,D] + bf16 [D,N] ---------------------
__global__ __launch_bounds__(256) void prep_hidden(const float* __restrict__ in,
                                                   unsigned short* __restrict__ hb,
                                                   unsigned short* __restrict__ hT) {
    __shared__ unsigned short tile[64][65];
    const int b = blockIdx.z;
    in += (size_t)b * N_ * D_;
    hb += (size_t)b * N_ * D_;
    hT += (size_t)b * D_ * N_;
    const int n0 = blockIdx.y * 64, d0 = blockIdx.x * 64;
    const int t = threadIdx.x;
    const int tr = t >> 4, tc = (t & 15) * 4;
#pragma unroll
    for (int q = 0; q < 4; ++q) {
        const int rr = q * 16 + tr;
        const float4 f = *(const float4*)&in[(size_t)(n0 + rr) * D_ + d0 + tc];
        unsigned short h0 = f2bf(f.x), h1 = f2bf(f.y), h2 = f2bf(f.z), h3 = f2bf(f.w);
        *(ushort4*)&hb[(size_t)(n0 + rr) * D_ + d0 + tc] = make_ushort4(h0, h1, h2, h3);
        tile[rr][tc + 0] = h0; tile[rr][tc + 1] = h1;
        tile[rr][tc + 2] = h2; tile[rr][tc + 3] = h3;
    }
    __syncthreads();
#pragma unroll
    for (int q = 0; q < 4; ++q) {
        const int cc = q * 16 + tr;
        ushort4 o = make_ushort4(tile[tc + 0][cc], tile[tc + 1][cc],
                                 tile[tc + 2][cc], tile[tc + 3][cc]);
        *(ushort4*)&hT[(size_t)(d0 + cc) * N_ + n0 + tc] = o;
    }
}

// ---------------- tiny: w[D,D] f32 -> wT[D,D] bf16 --------------------------
__global__ __launch_bounds__(256) void cast_wT(const float* __restrict__ w,
                                               unsigned short* __restrict__ wT) {
    const int gid = blockIdx.x * 256 + threadIdx.x;
    const int i = gid >> 8, j = gid & 255;
    wT[j * D_ + i] = f2bf(w[i * D_ + j]);
}

// ---- combine slabs: edge_h = (s0+s1)/(r0+r1) + eln; also f32 [D,E] T -------
__global__ __launch_bounds__(256) void reduce_pv(const float* __restrict__ slab,
                                                 const unsigned short* __restrict__ eln,
                                                 const float* __restrict__ rsump,
                                                 unsigned short* __restrict__ eh,
                                                 float* __restrict__ ehT) {
    __shared__ float tile[64][65];
    const int b = blockIdx.z;
    const float* s0 = slab + (size_t)b * E_ * D_;
    const float* s1 = slab + (size_t)(B_ + b) * E_ * D_;
    const int e0 = blockIdx.y * 64, d0 = blockIdx.x * 64;
    const int t = threadIdx.x;
    const int tr = t >> 4, tc = (t & 15) * 4;
#pragma unroll
    for (int q = 0; q < 4; ++q) {
        const int rr = q * 16 + tr;
        const int row = e0 + rr;
        const float4 v0 = *(const float4*)&s0[(size_t)row * D_ + d0 + tc];
        const float4 v1 = *(const float4*)&s1[(size_t)row * D_ + d0 + tc];
        const float inv = 1.0f / (rsump[(size_t)b * E_ + row] +
                                  rsump[(size_t)B_ * E_ + (size_t)b * E_ + row]);
        const ushort4 el = *(const ushort4*)&eln[(size_t)b * E_ * D_ + (size_t)row * D_ + d0 + tc];
        const float x0 = (v0.x + v1.x) * inv + bf2f(el.x);
        const float x1 = (v0.y + v1.y) * inv + bf2f(el.y);
        const float x2 = (v0.z + v1.z) * inv + bf2f(el.z);
        const float x3 = (v0.w + v1.w) * inv + bf2f(el.w);
        *(ushort4*)&eh[(size_t)b * E_ * D_ + (size_t)row * D_ + d0 + tc] =
            make_ushort4(f2bf(x0), f2bf(x1), f2bf(x2), f2bf(x3));
        tile[rr][tc + 0] = x0; tile[rr][tc + 1] = x1;
        tile[rr][tc + 2] = x2; tile[rr][tc + 3] = x3;
    }
    __syncthreads();
#pragma unroll
    for (int q = 0; q < 4; ++q) {
        const int cc = q * 16 + tr;
        float4 o = make_float4(tile[tc + 0][cc], tile[tc + 1][cc],
                               tile[tc + 2][cc], tile[tc + 3][cc]);
        *(float4*)&ehT[(size_t)b * D_ * E_ + (size_t)(d0 + cc) * E_ + e0 + tc] = o;
    }
}

// ---- edge_hsT[d,e] = ehT[d,e] / lsum[e]  (f32 in, bf16 out, [B,D,E]) -------
__global__ __launch_bounds__(256) void scale_ehT(const float* __restrict__ ehT,
                                                 const float* __restrict__ lsum,
                                                 unsigned short* __restrict__ ehs) {
    const size_t base = ((size_t)blockIdx.x * 256 + threadIdx.x) * 8;
    const int b = (int)(base / ((size_t)D_ * E_));
    const int e = (int)(base % E_);
    const float4 f0 = *(const float4*)&ehT[base];
    const float4 f1 = *(const float4*)&ehT[base + 4];
    const float4 l0 = *(const float4*)&lsum[(size_t)b * E_ + e];
    const float4 l1 = *(const float4*)&lsum[(size_t)b * E_ + e + 4];
    us8 o;
    o[0] = f2bf(f0.x / l0.x); o[1] = f2bf(f0.y / l0.y);
    o[2] = f2bf(f0.z / l0.z); o[3] = f2bf(f0.w / l0.w);
    o[4] = f2bf(f1.x / l1.x); o[5] = f2bf(f1.y / l1.y);
    o[6] = f2bf(f1.z / l1.z); o[7] = f2bf(f1.w / l1.w);
    *(us8*)&ehs[base] = o;
}

// ---------------- plain bf16 NT GEMM, K=256 (node_k / edge_k) ---------------
__global__ __launch_bounds__(256) void gemm_bf16(const short* __restrict__ A,
                                                 const short* __restrict__ Bm,
                                                 unsigned short* __restrict__ C) {
    __shared__ __align__(16) short ls[16896];
    short* lsA = ls;
    short* lsB = ls + 8192;
    const int m0 = blockIdx.y * 128, n0 = blockIdx.x * 128;
    const int tid = threadIdx.x, wid = tid >> 6, lane = tid & 63;
    const int l15 = lane & 15, kg = lane >> 4;
    const int wr = wid >> 1, wc = wid & 1;

    int raoff[4], rota[4], rboff[4], rotb[4];
#pragma unroll
    for (int i = 0; i < 4; ++i) {
        const int ra = wr * 64 + i * 16 + l15;
        raoff[i] = ra * 64; rota[i] = kg + (ra >> 1);
        const int rb = wc * 64 + i * 16 + l15;
        rboff[i] = rb * 64; rotb[i] = kg + (rb >> 1);
    }
    const f32x4 zero = {0.f, 0.f, 0.f, 0.f};
    f32x4 acc[4][4];
#pragma unroll
    for (int i = 0; i < 4; ++i)
#pragma unroll
        for (int j = 0; j < 4; ++j) acc[i][j] = zero;

    for (int kt = 0; kt < 256; kt += 64) {
        __syncthreads();
#pragma unroll
        for (int q = 0; q < 4; ++q) {
            const int c = q * 256 + tid;
            const int r = c >> 3;
            const int kc = ((c & 7) - (r >> 1)) & 7;
            const short* ga = A + (size_t)(m0 + r) * 256 + kt + kc * 8;
            __builtin_amdgcn_global_load_lds((const AS1 void*)ga,
                (AS3 void*)(lsA + (q * 256 + wid * 64) * 8), 16, 0, 0);
            const short* gb = Bm + (size_t)(n0 + r) * 256 + kt + kc * 8;
            __builtin_amdgcn_global_load_lds((const AS1 void*)gb,
                (AS3 void*)(lsB + (q * 256 + wid * 64) * 8), 16, 0, 0);
        }
        __syncthreads();
#pragma unroll
        for (int s = 0; s < 2; ++s) {
            bf16x8 fa[4], fb[4];
#pragma unroll
            for (int i = 0; i < 4; ++i)
                fa[i] = *(const bf16x8*)(lsA + raoff[i] + (((s * 4 + rota[i]) & 7) << 3));
#pragma unroll
            for (int j = 0; j < 4; ++j)
                fb[j] = *(const bf16x8*)(lsB + rboff[j] + (((s * 4 + rotb[j]) & 7) << 3));
#pragma unroll
            for (int i = 0; i < 4; ++i)
#pragma unroll
                for (int j = 0; j < 4; ++j)
                    acc[i][j] = __builtin_amdgcn_mfma_f32_16x16x32_bf16(fa[i], fb[j], acc[i][j], 0, 0, 0);
        }
    }
    __syncthreads();
#pragma unroll
    for (int i = 0; i < 4; ++i)
#pragma unroll
        for (int r = 0; r < 4; ++r) {
            const int rowfull = wr * 64 + i * 16 + kg * 4 + r;
#pragma unroll
            for (int j = 0; j < 4; ++j) {
                const int cl = wc * 64 + j * 16 + l15;
                ls[rowfull * 132 + cl] = (short)f2bf(acc[i][j][r]);
            }
        }
    __syncthreads();
#pragma unroll
    for (int si = 0; si < 8; ++si) {
        const int row = (tid >> 4) + si * 16;
        const int col = (tid & 15) * 8;
        us8 val = *(us8*)&ls[row * 132 + col];
        *(us8*)&C[(size_t)(m0 + row) * D_ + n0 + col] = val;
    }
}

// ---------------- fused score->exp->PV kernel -------------------------------
// MODE 0: lsum only, m=32 tiles, double-buffered b1 (R13 layout).
// MODE 1: stage 1, m=64 tiles (R12 layout), n-loop split by blockIdx.z;
//         writes raw PV slab f32 [2][B][E][D] + partial rsum [2][B][E].
// MODE 2: stage 2, m=64 tiles (R12 layout); out f32 [B,N,D].
// MODE1/2 per-tile order: score(b1) -> P -> bar(a) -> issue b1(t+1) -> PV ->
// bar(b) -> issue b2(t+1): every staging overlaps a compute phase.
template <int MODE>
__global__ __launch_bounds__(256, 2) void fused_attn(
        const short* __restrict__ A, const short* __restrict__ B1,
        const short* __restrict__ B2, const uint32_t* __restrict__ bits,
        void* __restrict__ out1, float* __restrict__ sums,
        int KN, float scale) {
    // shorts: MODE1/2: b1 0..16383, b2 16384..32767, P 32768..36863,
    //         rsx(f32[128]) 36864..37119.  MODE0: b1[2] 0..32767, rsx 32768.
    __shared__ __align__(16) short ls[(MODE == 0) ? 33024 : ((MODE == 1) ? 37120 : 36864)];
    const int b = blockIdx.x;      // batch; linear id % 8 == b -> XCD affinity
    const int m0 = blockIdx.y * ((MODE == 0) ? 32 : 64);
    const int MA = (MODE == 2) ? N_ : E_;
    const short* Ab = A + (size_t)b * MA * D_;
    const short* B1b = B1 + (size_t)b * KN * D_;
    const short* B2b = (MODE != 0) ? (B2 + (size_t)b * D_ * KN) : nullptr;
    const uint32_t* bb = bits + (size_t)b * E_ * (N_ / 32);

    const int tid = threadIdx.x, wid = tid >> 6, lane = tid & 63;
    const int l15 = lane & 15, kg = lane >> 4;
    const int wv = wid >> 1, ww2 = wid & 1;  // MODE1/2 wave coords
    const int ww4 = wid;                     // MODE0 wave coord

    const int kbase = (MODE == 1) ? blockIdx.z * (KN >> 1) : 0;
    const int NT = ((MODE == 1) ? (KN >> 1) : KN) / 64;

    // A fragments in registers, full K=256
    bf16x8 fa[2][8];
#pragma unroll
    for (int mf = 0; mf < 2; ++mf) {
        const int arow = (MODE == 0) ? (m0 + mf * 16 + l15)
                                     : (m0 + wv * 32 + mf * 16 + l15);
        const size_t ar = (size_t)arow * D_;
#pragma unroll
        for (int kf = 0; kf < 8; ++kf)
            fa[mf][kf] = *(const bf16x8*)(Ab + ar + (kf * 4 + kg) * 8);
    }

    const f32x4 zero = {0.f, 0.f, 0.f, 0.f};
    f32x4 acco[2][8];
    if (MODE != 0) {
#pragma unroll
        for (int mf = 0; mf < 2; ++mf)
#pragma unroll
            for (int jf = 0; jf < 8; ++jf) acco[mf][jf] = zero;
    }
    float rs[2][4] = {{0.f, 0.f, 0.f, 0.f}, {0.f, 0.f, 0.f, 0.f}};

    short* Pp = ls + 32768;  // MODE1/2

#define STAGE_B1(base_, tt) do {                                               \
        const int kt_ = kbase + (tt) * 64;                                     \
        _Pragma("unroll")                                                      \
        for (int q = 0; q < 8; ++q) {                                          \
            const int c_ = q * 256 + tid;                                      \
            const int r_ = c_ >> 5;                                            \
            const int ck_ = (c_ & 31) ^ (r_ & 31);                             \
            __builtin_amdgcn_global_load_lds(                                  \
                (const AS1 void*)(B1b + (size_t)(kt_ + r_) * D_ + ck_ * 8),    \
                (AS3 void*)((base_) + (q * 256 + wid * 64) * 8), 16, 0, 0);    \
        }                                                                      \
    } while (0)

#define STAGE_B2(tt) do {                                                      \
        const int kt_ = kbase + (tt) * 64;                                     \
        _Pragma("unroll")                                                      \
        for (int q = 0; q < 8; ++q) {                                          \
            const int c_ = q * 256 + tid;                                      \
            const int r_ = c_ >> 3;                                            \
            const int ck_ = (c_ & 7) ^ ((r_ >> 1) & 7);                        \
            __builtin_amdgcn_global_load_lds(                                  \
                (const AS1 void*)(B2b + (size_t)r_ * KN + kt_ + ck_ * 8),      \
                (AS3 void*)(ls + 16384 + (q * 256 + wid * 64) * 8), 16, 0, 0); \
        }                                                                      \
    } while (0)

    int cur = 0;
    STAGE_B1(ls, 0);
    if (MODE != 0) STAGE_B2(0);
    __syncthreads();

    for (int t = 0; t < NT; ++t) {
        const int kt0 = kbase + t * 64;
        if (MODE == 0) {
            // ---- double-buffered score-only loop
            if (t + 1 < NT) STAGE_B1(ls + (cur ^ 1) * 16384, t + 1);
            const short* b1c = ls + cur * 16384;
            f32x4 accs[2];
            accs[0] = zero; accs[1] = zero;
            const int rb = ww4 * 16 + l15;
            const int xb = kg ^ (rb & 31);
#pragma unroll
            for (int kf = 0; kf < 8; ++kf) {
                const bf16x8 fb = *(const bf16x8*)(b1c + rb * 256 + ((kf * 4) ^ xb) * 8);
                accs[0] = __builtin_amdgcn_mfma_f32_16x16x32_bf16(fa[0][kf], fb, accs[0], 0, 0, 0);
                accs[1] = __builtin_amdgcn_mfma_f32_16x16x32_bf16(fa[1][kf], fb, accs[1], 0, 0, 0);
            }
            uint64_t mw[2][4];
#pragma unroll
            for (int mf = 0; mf < 2; ++mf)
#pragma unroll
                for (int r = 0; r < 4; ++r) {
                    const int row = m0 + mf * 16 + kg * 4 + r;
                    mw[mf][r] = *(const uint64_t*)&bb[(size_t)row * (N_ / 32) + (kt0 >> 5)];
                }
#pragma unroll
            for (int mf = 0; mf < 2; ++mf)
#pragma unroll
                for (int r = 0; r < 4; ++r) {
                    float v = accs[mf][r] * scale;
                    const uint32_t bit = (uint32_t)(mw[mf][r] >> (ww4 * 16 + l15)) & 1u;
                    rs[mf][r] += bit ? __expf(v) : 0.f;
                }
            __syncthreads();  // drains t+1 staging; ends reads of buf cur
            cur ^= 1;
        } else {
            // ---- score GEMM on b1 (rows wv*32+mf*16, cols ww2*32+jf*16)
            f32x4 accs[2][2];
            accs[0][0] = zero; accs[0][1] = zero; accs[1][0] = zero; accs[1][1] = zero;
            const int rb0 = ww2 * 32 + l15, rb1 = ww2 * 32 + 16 + l15;
            const int x0 = kg ^ (rb0 & 31), x1 = kg ^ (rb1 & 31);
#pragma unroll
            for (int kf = 0; kf < 8; ++kf) {
                const bf16x8 fb0 = *(const bf16x8*)(ls + rb0 * 256 + ((kf * 4) ^ x0) * 8);
                const bf16x8 fb1 = *(const bf16x8*)(ls + rb1 * 256 + ((kf * 4) ^ x1) * 8);
                accs[0][0] = __builtin_amdgcn_mfma_f32_16x16x32_bf16(fa[0][kf], fb0, accs[0][0], 0, 0, 0);
                accs[1][0] = __builtin_amdgcn_mfma_f32_16x16x32_bf16(fa[1][kf], fb0, accs[1][0], 0, 0, 0);
                accs[0][1] = __builtin_amdgcn_mfma_f32_16x16x32_bf16(fa[0][kf], fb1, accs[0][1], 0, 0, 0);
                accs[1][1] = __builtin_amdgcn_mfma_f32_16x16x32_bf16(fa[1][kf], fb1, accs[1][1], 0, 0, 0);
            }
            // ---- mask + exp (+rs) + P
            uint64_t mw[2][4];
            uint32_t cw[2];
            if (MODE == 1) {
#pragma unroll
                for (int mf = 0; mf < 2; ++mf)
#pragma unroll
                    for (int r = 0; r < 4; ++r) {
                        const int row = m0 + wv * 32 + mf * 16 + kg * 4 + r;
                        mw[mf][r] = *(const uint64_t*)&bb[(size_t)row * (N_ / 32) + (kt0 >> 5)];
                    }
            } else {
#pragma unroll
                for (int jf = 0; jf < 2; ++jf) {
                    const int col = kt0 + ww2 * 32 + jf * 16 + l15;
                    cw[jf] = bb[(size_t)col * (N_ / 32) + ((m0 + wv * 32) >> 5)];
                }
            }
#pragma unroll
            for (int mf = 0; mf < 2; ++mf)
#pragma unroll
                for (int jf = 0; jf < 2; ++jf)
#pragma unroll
                    for (int r = 0; r < 4; ++r) {
                        float v = accs[mf][jf][r] * scale;
                        uint32_t bit;
                        if (MODE == 1)
                            bit = (uint32_t)(mw[mf][r] >> (ww2 * 32 + jf * 16 + l15)) & 1u;
                        else
                            bit = (cw[jf] >> (mf * 16 + kg * 4 + r)) & 1u;
                        v = bit ? __expf(v) : 0.f;
                        if (MODE == 1) rs[mf][r] += v;
                        const int prow = wv * 32 + mf * 16 + kg * 4 + r;
                        const int pcol = ww2 * 32 + jf * 16 + l15;
                        Pp[prow * 64 + (((pcol >> 3) ^ ((prow >> 1) & 7)) * 8) + (pcol & 7)] =
                            (short)f2bf(v);
                    }
            __syncthreads();  // (a) P visible; drains b2(t) prefetch
            if (t + 1 < NT) STAGE_B1(ls, t + 1);  // overlaps PV
            // ---- PV GEMM (P rows wv*32, d-cols ww2*128+jf*16)
            const short* b2c = ls + 16384;
            const int pr0 = wv * 32 + l15, pr1 = wv * 32 + 16 + l15;
            const int px0 = kg ^ ((pr0 >> 1) & 7), px1 = kg ^ ((pr1 >> 1) & 7);
#pragma unroll
            for (int kf2 = 0; kf2 < 2; ++kf2) {
                const bf16x8 pa0 = *(const bf16x8*)(Pp + pr0 * 64 + ((kf2 * 4) ^ px0) * 8);
                const bf16x8 pa1 = *(const bf16x8*)(Pp + pr1 * 64 + ((kf2 * 4) ^ px1) * 8);
#pragma unroll
                for (int jf = 0; jf < 8; ++jf) {
                    const int rh = ww2 * 128 + jf * 16 + l15;
                    const bf16x8 fbh = *(const bf16x8*)(b2c + rh * 64 +
                        (((kf2 * 4 + kg) ^ ((rh >> 1) & 7))) * 8);
                    acco[0][jf] = __builtin_amdgcn_mfma_f32_16x16x32_bf16(pa0, fbh, acco[0][jf], 0, 0, 0);
                    acco[1][jf] = __builtin_amdgcn_mfma_f32_16x16x32_bf16(pa1, fbh, acco[1][jf], 0, 0, 0);
                }
            }
            __syncthreads();  // (b) drains b1(t+1); PV reads done
            if (t + 1 < NT) STAGE_B2(t + 1);  // overlaps next score
        }
    }
#undef STAGE_B1
#undef STAGE_B2

    // ---- epilogues ----
    if (MODE == 0) {
        float* rsx = (float*)(ls + 32768);  // [4][32]
#pragma unroll
        for (int mf = 0; mf < 2; ++mf)
#pragma unroll
            for (int r = 0; r < 4; ++r) {
                float s = rs[mf][r];
                s += __shfl_xor(s, 1, 64); s += __shfl_xor(s, 2, 64);
                s += __shfl_xor(s, 4, 64); s += __shfl_xor(s, 8, 64);
                if (l15 == 0) rsx[ww4 * 32 + mf * 16 + kg * 4 + r] = s;
            }
        __syncthreads();
        if (tid < 32)
            sums[(size_t)b * E_ + m0 + tid] =
                rsx[tid] + rsx[32 + tid] + rsx[64 + tid] + rsx[96 + tid];
    } else if (MODE == 1) {
        // partial rsum
        float* rsx = (float*)(ls + 36864);  // [2][64]
#pragma unroll
        for (int mf = 0; mf < 2; ++mf)
#pragma unroll
            for (int r = 0; r < 4; ++r) {
                float s = rs[mf][r];
                s += __shfl_xor(s, 1, 64); s += __shfl_xor(s, 2, 64);
                s += __shfl_xor(s, 4, 64); s += __shfl_xor(s, 8, 64);
                if (l15 == 0) rsx[ww2 * 64 + wv * 32 + mf * 16 + kg * 4 + r] = s;
            }
        __syncthreads();
        if (tid < 64)
            sums[(size_t)blockIdx.z * B_ * E_ + (size_t)b * E_ + m0 + tid] =
                rsx[tid] + rsx[64 + tid];
        // raw PV slab write via LDS repack
        float* lsF = (float*)ls;  // [64][256] f32 (aliases b1+b2)
#pragma unroll
        for (int mf = 0; mf < 2; ++mf)
#pragma unroll
            for (int r = 0; r < 4; ++r) {
                const int row = wv * 32 + mf * 16 + kg * 4 + r;
#pragma unroll
                for (int jf = 0; jf < 8; ++jf)
                    lsF[row * 256 + ww2 * 128 + jf * 16 + l15] = acco[mf][jf][r];
            }
        __syncthreads();
        float* sl = (float*)out1 + ((size_t)blockIdx.z * B_ + b) * (size_t)E_ * D_ +
                    (size_t)m0 * D_;
#pragma unroll
        for (int p = 0; p < 16; ++p) {
            const int lin = p * 256 + tid;
            const int row = lin >> 6, c4 = (lin & 63) * 4;
            *(float4*)&sl[(size_t)row * D_ + c4] = *(const float4*)&lsF[row * 256 + c4];
        }
    } else {
        float* lsF = (float*)ls;  // [64][256] f32
#pragma unroll
        for (int mf = 0; mf < 2; ++mf)
#pragma unroll
            for (int r = 0; r < 4; ++r) {
                const int row = wv * 32 + mf * 16 + kg * 4 + r;
#pragma unroll
                for (int jf = 0; jf < 8; ++jf)
                    lsF[row * 256 + ww2 * 128 + jf * 16 + l15] = acco[mf][jf][r];
            }
        __syncthreads();
        float* ob = (float*)out1 + (size_t)b * N_ * D_;
#pragma unroll
        for (int p = 0; p < 16; ++p) {
            const int lin = p * 256 + tid;
            const int row = lin >> 6, c4 = (lin & 63) * 4;
            *(float4*)&ob[(size_t)(m0 + row) * D_ + c4] = *(const float4*)&lsF[row * 256 + c4];
        }
    }
}

// ---------------------------------------------------------------------------
extern "C" void kernel_launch(void* const* d_in, const int* in_sizes, int n_in,
                              void* d_out, int out_size, void* d_ws, size_t ws_size,
                              hipStream_t stream) {
    const float* hidden = (const float*)d_in[0];    // [B,N,D]
    const int* ht = (const int*)d_in[1];            // [B,E,N]
    const float* edge_emb = (const float*)d_in[2];  // [B,E,D]
    const float* wnk = (const float*)d_in[3];       // [D,D]
    const float* wek = (const float*)d_in[4];       // [D,D]
    const float* gamma = (const float*)d_in[5];     // [D]
    const float* beta = (const float*)d_in[6];      // [D]
    float* out = (float*)d_out;                     // [B,N,D]
    (void)in_sizes; (void)n_in; (void)out_size; (void)ws_size;

    char* w = (char*)d_ws;
    unsigned short* hidden_bf = (unsigned short*)w;  w += (size_t)B_ * N_ * D_ * 2;
    unsigned short* hiddenT_bf = (unsigned short*)w; w += (size_t)B_ * D_ * N_ * 2;
    unsigned short* node_k_bf = (unsigned short*)w;  w += (size_t)B_ * N_ * D_ * 2;
    unsigned short* eln_bf = (unsigned short*)w;     w += (size_t)B_ * E_ * D_ * 2;
    unsigned short* edge_h_bf = (unsigned short*)w;  w += (size_t)B_ * E_ * D_ * 2;
    float* ehT_f32 = (float*)w;                      w += (size_t)B_ * D_ * E_ * 4;
    unsigned short* ehsT_bf = (unsigned short*)w;    w += (size_t)B_ * D_ * E_ * 2;
    unsigned short* edge_k_bf = (unsigned short*)w;  w += (size_t)B_ * E_ * D_ * 2;
    float* slabs = (float*)w;                        w += (size_t)2 * B_ * E_ * D_ * 4;
    float* rsump = (float*)w;                        w += (size_t)2 * B_ * E_ * 4;
    uint32_t* bits = (uint32_t*)w;                   w += (size_t)B_ * E_ * (N_ / 32) * 4;
    float* lsum = (float*)w;                         w += (size_t)B_ * E_ * 4;
    unsigned short* wnkT = (unsigned short*)w;       w += (size_t)D_ * D_ * 2;
    unsigned short* wekT = (unsigned short*)w;       w += (size_t)D_ * D_ * 2;

    const float scale = 0.0625f;  // 1/sqrt(256)

    // prep
    prep_hidden<<<dim3(D_ / 64, N_ / 64, B_), 256, 0, stream>>>(hidden, hidden_bf, hiddenT_bf);
    cast_wT<<<D_ * D_ / 256, 256, 0, stream>>>(wnk, wnkT);
    cast_wT<<<D_ * D_ / 256, 256, 0, stream>>>(wek, wekT);
    ln_kernel<<<B_ * E_, 256, 0, stream>>>(edge_emb, gamma, beta, eln_bf);
    pack_mask<<<B_ * E_, 256, 0, stream>>>(ht, bits);

    // node_k = hidden @ wnk
    gemm_bf16<<<dim3(D_ / 128, (B_ * N_) / 128), 256, 0, stream>>>(
        (const short*)hidden_bf, (const short*)wnkT, node_k_bf);
    // fused stage 1 (n-split 2-way): raw PV slabs + partial rsums
    fused_attn<1><<<dim3(8, E_ / 64, 2), 256, 0, stream>>>(
        (const short*)eln_bf, (const short*)node_k_bf, (const short*)hiddenT_bf,
        bits, slabs, rsump, N_, scale);
    // combine: edge_h = (s0+s1)/(r0+r1) + eln -> bf16 [E,D] + f32 [D,E]
    reduce_pv<<<dim3(D_ / 64, E_ / 64, B_), 256, 0, stream>>>(
        slabs, eln_bf, rsump, edge_h_bf, ehT_f32);
    // edge_k = edge_h @ wek
    gemm_bf16<<<dim3(D_ / 128, (B_ * E_) / 128), 256, 0, stream>>>(
        (const short*)edge_h_bf, (const short*)wekT, edge_k_bf);
    // lsum[e] = sum_n exp(mask(node_k . edge_k * scale))
    fused_attn<0><<<dim3(8, E_ / 32), 256, 0, stream>>>(
        (const short*)edge_k_bf, (const short*)node_k_bf, nullptr,
        bits, nullptr, lsum, N_, scale);
    // ehsT[d,e] = ehT/lsum
    scale_ehT<<<(B_ * D_ * E_) / (256 * 8), 256, 0, stream>>>(ehT_f32, lsum, ehsT_bf);
    // fused stage 2: out[n,d] = sum_e exp(s2[n,e]) * ehsT[d,e]
    fused_attn<2><<<dim3(8, N_ / 64), 256, 0, stream>>>(
        (const short*)node_k_bf, (const short*)edge_k_bf, (const short*)ehsT_bf,
        bits, out, nullptr, E_, scale);
}

// Round 9
// 751.150 us; speedup vs baseline: 1.1460x; 1.1460x over previous
//
#include <hip/hip_runtime.h>
#include <hip/hip_bf16.h>
#include <stdint.h>

// R15: consolidation. Exact R7 pipeline (session best, 773 µs) with the one
// strictly-better component verified since: int4+nibble pack_mask (R8/R9,
// passed correctness twice). Fusion arc (R12-R14) abandoned: all variants
// lost to the materialized pipeline (barrier-drain serialization at 2
// blocks/CU; B-slab re-reads per 64-row tile). No swizzles (R8 neutral),
// no wide PV (R9 occupancy-starved).

#define B_ 8
#define N_ 4096
#define E_ 2048
#define D_ 256
#define INF_SUB (-9.0e15f)

typedef short bf16x8 __attribute__((ext_vector_type(8)));
typedef float f32x4 __attribute__((ext_vector_type(4)));
typedef unsigned short us8 __attribute__((ext_vector_type(8)));

#define AS1 __attribute__((address_space(1)))
#define AS3 __attribute__((address_space(3)))

__device__ __forceinline__ unsigned short f2bf(float f) {
    union { float f; unsigned int u; } v; v.f = f;
    unsigned int r = v.u + 0x7fffu + ((v.u >> 16) & 1u);
    return (unsigned short)(r >> 16);
}
__device__ __forceinline__ float bf2f(unsigned short h) {
    union { unsigned int u; float f; } v; v.u = ((unsigned int)h) << 16;
    return v.f;
}
__device__ __forceinline__ float waveReduceSum(float v) {
#pragma unroll
    for (int o = 32; o > 0; o >>= 1) v += __shfl_xor(v, o, 64);
    return v;
}

// ---------------- LayerNorm over D=256 -> bf16 ------------------------------
__global__ __launch_bounds__(256) void ln_kernel(const float* __restrict__ x,
                                                 const float* __restrict__ gamma,
                                                 const float* __restrict__ beta,
                                                 unsigned short* __restrict__ yb) {
    __shared__ float red[8];
    const int row = blockIdx.x;
    const int t = threadIdx.x;
    const int lane = t & 63, wid = t >> 6;
    const float v = x[(size_t)row * D_ + t];
    float s = waveReduceSum(v);
    if (lane == 0) red[wid] = s;
    __syncthreads();
    const float mu = (red[0] + red[1] + red[2] + red[3]) * (1.0f / D_);
    const float d = v - mu;
    float s2 = waveReduceSum(d * d);
    if (lane == 0) red[4 + wid] = s2;
    __syncthreads();
    const float var = (red[4] + red[5] + red[6] + red[7]) * (1.0f / D_);
    yb[(size_t)row * D_ + t] = f2bf(gamma[t] * d * rsqrtf(var + 1e-5f) + beta[t]);
}

// ---------------- pack ht -> bitmask: bits[b][e][n>>5] bit (n&31) -----------
// int4 loads (16B/lane) + nibble compaction through LDS (R8-verified).
__global__ __launch_bounds__(256) void pack_mask(const int* __restrict__ ht,
                                                 uint32_t* __restrict__ bits) {
    __shared__ __align__(8) unsigned char nib[256];
    const int row = blockIdx.x;
    const int t = threadIdx.x;
    const int* hrow = ht + (size_t)row * N_;
    uint32_t* brow = bits + (size_t)row * (N_ / 32);
#pragma unroll
    for (int it = 0; it < 4; ++it) {
        const int4 v = *(const int4*)&hrow[it * 1024 + t * 4];
        unsigned char n = (unsigned char)((v.x > 0) | ((v.y > 0) << 1) |
                                          ((v.z > 0) << 2) | ((v.w > 0) << 3));
        nib[t] = n;
        __syncthreads();
        if (t < 32) {
            uint64_t x = *(const uint64_t*)&nib[t * 8];
            x = (x | (x >> 4)) & 0x00FF00FF00FF00FFull;
            x = (x | (x >> 8)) & 0x0000FFFF0000FFFFull;
            brow[it * 32 + t] = (uint32_t)(x | (x >> 16));
        }
        __syncthreads();
    }
}

// ---------------- fp32 [N,D] -> bf16 [N,D] + bf16 [D,N] ---------------------
__global__ __launch_bounds__(256) void prep_hidden(const float* __restrict__ in,
                                                   unsigned short* __restrict__ hb,
                                                   unsigned short* __restrict__ hT) {
    __shared__ unsigned short tile[64][65];
    const int b = blockIdx.z;
    in += (size_t)b * N_ * D_;
    hb += (size_t)b * N_ * D_;
    hT += (size_t)b * D_ * N_;
    const int n0 = blockIdx.y * 64, d0 = blockIdx.x * 64;
    const int t = threadIdx.x;
    const int tr = t >> 4, tc = (t & 15) * 4;
#pragma unroll
    for (int q = 0; q < 4; ++q) {
        const int rr = q * 16 + tr;
        const float4 f = *(const float4*)&in[(size_t)(n0 + rr) * D_ + d0 + tc];
        unsigned short h0 = f2bf(f.x), h1 = f2bf(f.y), h2 = f2bf(f.z), h3 = f2bf(f.w);
        *(ushort4*)&hb[(size_t)(n0 + rr) * D_ + d0 + tc] = make_ushort4(h0, h1, h2, h3);
        tile[rr][tc + 0] = h0; tile[rr][tc + 1] = h1;
        tile[rr][tc + 2] = h2; tile[rr][tc + 3] = h3;
    }
    __syncthreads();
#pragma unroll
    for (int q = 0; q < 4; ++q) {
        const int cc = q * 16 + tr;
        ushort4 o = make_ushort4(tile[tc + 0][cc], tile[tc + 1][cc],
                                 tile[tc + 2][cc], tile[tc + 3][cc]);
        *(ushort4*)&hT[(size_t)(d0 + cc) * N_ + n0 + tc] = o;
    }
}

// ---------------- tiny: w[D,D] f32 -> wT[D,D] bf16 --------------------------
__global__ __launch_bounds__(256) void cast_wT(const float* __restrict__ w,
                                               unsigned short* __restrict__ wT) {
    const int gid = blockIdx.x * 256 + threadIdx.x;
    const int i = gid >> 8, j = gid & 255;
    wT[j * D_ + i] = f2bf(w[i * D_ + j]);
}

// ---- PV slab reduce: edge_h = (slab0+slab1)/rsum + eln; also f32 [D,E] T ---
__global__ __launch_bounds__(256) void reduce_pv(const float* __restrict__ slab,
                                                 const unsigned short* __restrict__ eln,
                                                 const float* __restrict__ rsum,
                                                 unsigned short* __restrict__ eh,
                                                 float* __restrict__ ehT) {
    __shared__ float tile[64][65];
    const int b = blockIdx.z;
    const float* s0 = slab + (size_t)(b * 2) * E_ * D_;
    const float* s1 = slab + (size_t)(b * 2 + 1) * E_ * D_;
    const int e0 = blockIdx.y * 64, d0 = blockIdx.x * 64;
    const int t = threadIdx.x;
    const int tr = t >> 4, tc = (t & 15) * 4;
#pragma unroll
    for (int q = 0; q < 4; ++q) {
        const int rr = q * 16 + tr;
        const int row = e0 + rr;
        const float4 v0 = *(const float4*)&s0[(size_t)row * D_ + d0 + tc];
        const float4 v1 = *(const float4*)&s1[(size_t)row * D_ + d0 + tc];
        const float inv = 1.0f / rsum[(size_t)b * E_ + row];
        const ushort4 el = *(const ushort4*)&eln[(size_t)b * E_ * D_ + (size_t)row * D_ + d0 + tc];
        const float x0 = (v0.x + v1.x) * inv + bf2f(el.x);
        const float x1 = (v0.y + v1.y) * inv + bf2f(el.y);
        const float x2 = (v0.z + v1.z) * inv + bf2f(el.z);
        const float x3 = (v0.w + v1.w) * inv + bf2f(el.w);
        *(ushort4*)&eh[(size_t)b * E_ * D_ + (size_t)row * D_ + d0 + tc] =
            make_ushort4(f2bf(x0), f2bf(x1), f2bf(x2), f2bf(x3));
        tile[rr][tc + 0] = x0; tile[rr][tc + 1] = x1;
        tile[rr][tc + 2] = x2; tile[rr][tc + 3] = x3;
    }
    __syncthreads();
#pragma unroll
    for (int q = 0; q < 4; ++q) {
        const int cc = q * 16 + tr;
        float4 o = make_float4(tile[tc + 0][cc], tile[tc + 1][cc],
                               tile[tc + 2][cc], tile[tc + 3][cc]);
        *(float4*)&ehT[(size_t)b * D_ * E_ + (size_t)(d0 + cc) * E_ + e0 + tc] = o;
    }
}

// ---- edge_hsT[d,e] = ehT[d,e] / lsum[e]  (f32 in, bf16 out, [B,D,E]) -------
__global__ __launch_bounds__(256) void scale_ehT(const float* __restrict__ ehT,
                                                 const float* __restrict__ lsum,
                                                 unsigned short* __restrict__ ehs) {
    const size_t base = ((size_t)blockIdx.x * 256 + threadIdx.x) * 8;
    const int b = (int)(base / ((size_t)D_ * E_));
    const int e = (int)(base % E_);
    const float4 f0 = *(const float4*)&ehT[base];
    const float4 f1 = *(const float4*)&ehT[base + 4];
    const float4 l0 = *(const float4*)&lsum[(size_t)b * E_ + e];
    const float4 l1 = *(const float4*)&lsum[(size_t)b * E_ + e + 4];
    us8 o;
    o[0] = f2bf(f0.x / l0.x); o[1] = f2bf(f0.y / l0.y);
    o[2] = f2bf(f0.z / l0.z); o[3] = f2bf(f0.w / l0.w);
    o[4] = f2bf(f1.x / l1.x); o[5] = f2bf(f1.y / l1.y);
    o[6] = f2bf(f1.z / l1.z); o[7] = f2bf(f1.w / l1.w);
    *(us8*)&ehs[base] = o;
}

// ---------------- MFMA NT GEMM: C[m,n] = sum_k A[m,k]*Bt[n,k] ---------------
// 128x128 tile, BK=64, global_load_lds w=16, chunk-rotate swizzle mod 8.
// M_MASK stores bf16(exp(masked v)) (masked -> 0.0). RSUM: row exp-sums.
// CSUM: column exp-sums.
#define M_BF16 0
#define M_MASK 1
#define M_F32 2

template <int MODE, int MASKOR, int RSUM, int SPLIT, int CSUM>
__global__ __launch_bounds__(256) void mfma_gemm_nt(
        const short* __restrict__ A, const short* __restrict__ Bm,
        void* __restrict__ Cv, const uint32_t* __restrict__ bits,
        float* __restrict__ sums,
        int K, int ldc, size_t sA, size_t sB, size_t sC, float scale) {
    __shared__ __align__(16) short ls[(MODE == M_F32) ? 16384 : 16896];
    __shared__ uint32_t mwords[MASKOR ? 512 : 4];
    short* lsA = ls;              // 128 x 64 bf16 = 16 KB
    short* lsB = ls + 8192;       // 128 x 64 bf16 = 16 KB
    const int zb = blockIdx.z;
    const int b = SPLIT ? (zb >> 1) : zb;
    A += (size_t)b * sA;
    Bm += (size_t)b * sB;
    const int m0 = blockIdx.y * 128, n0 = blockIdx.x * 128;
    const int tid = threadIdx.x, wid = tid >> 6, lane = tid & 63;
    const int l15 = lane & 15, kg = lane >> 4;
    const int wr = wid >> 1, wc = wid & 1;

    if (MASKOR) {
        const uint32_t* bb = bits + (size_t)b * E_ * (N_ / 32);
#pragma unroll
        for (int q = 0; q < 2; ++q) {
            const int idx = q * 256 + tid;
            mwords[idx] = (MASKOR == 1)
                ? bb[(size_t)(m0 + (idx >> 2)) * (N_ / 32) + (n0 >> 5) + (idx & 3)]
                : bb[(size_t)(n0 + (idx >> 2)) * (N_ / 32) + (m0 >> 5) + (idx & 3)];
        }
    }

    int raoff[4], rota[4], rboff[4], rotb[4];
#pragma unroll
    for (int i = 0; i < 4; ++i) {
        const int ra = wr * 64 + i * 16 + l15;
        raoff[i] = ra * 64; rota[i] = kg + (ra >> 1);
        const int rb = wc * 64 + i * 16 + l15;
        rboff[i] = rb * 64; rotb[i] = kg + (rb >> 1);
    }
    const f32x4 zero = {0.f, 0.f, 0.f, 0.f};
    f32x4 acc[4][4];
#pragma unroll
    for (int i = 0; i < 4; ++i)
#pragma unroll
        for (int j = 0; j < 4; ++j) acc[i][j] = zero;

    const int kt0 = SPLIT ? (zb & 1) * (K >> 1) : 0;
    const int ktE = SPLIT ? kt0 + (K >> 1) : K;
    for (int kt = kt0; kt < ktE; kt += 64) {
        __syncthreads();
#pragma unroll
        for (int q = 0; q < 4; ++q) {
            const int c = q * 256 + tid;
            const int r = c >> 3;
            const int kc = ((c & 7) - (r >> 1)) & 7;
            const short* ga = A + (size_t)(m0 + r) * K + kt + kc * 8;
            __builtin_amdgcn_global_load_lds((const AS1 void*)ga,
                (AS3 void*)(lsA + (q * 256 + wid * 64) * 8), 16, 0, 0);
            const short* gb = Bm + (size_t)(n0 + r) * K + kt + kc * 8;
            __builtin_amdgcn_global_load_lds((const AS1 void*)gb,
                (AS3 void*)(lsB + (q * 256 + wid * 64) * 8), 16, 0, 0);
        }
        __syncthreads();
#pragma unroll
        for (int s = 0; s < 2; ++s) {
            bf16x8 fa[4], fb[4];
#pragma unroll
            for (int i = 0; i < 4; ++i)
                fa[i] = *(const bf16x8*)(lsA + raoff[i] + (((s * 4 + rota[i]) & 7) << 3));
#pragma unroll
            for (int j = 0; j < 4; ++j)
                fb[j] = *(const bf16x8*)(lsB + rboff[j] + (((s * 4 + rotb[j]) & 7) << 3));
#pragma unroll
            for (int i = 0; i < 4; ++i)
#pragma unroll
                for (int j = 0; j < 4; ++j)
                    acc[i][j] = __builtin_amdgcn_mfma_f32_16x16x32_bf16(fa[i], fb[j], acc[i][j], 0, 0, 0);
        }
    }

    __syncthreads();  // fragment reads done; ls free for repack

    if (MODE == M_F32) {
        float* C = (float*)Cv + (SPLIT ? (size_t)zb * sC : (size_t)b * sC);
        float* lsF = (float*)ls;
#pragma unroll
        for (int h = 0; h < 4; ++h) {
            if (wr == (h >> 1)) {
#pragma unroll
                for (int ii = 0; ii < 2; ++ii) {
                    const int i = (h & 1) * 2 + ii;
#pragma unroll
                    for (int j = 0; j < 4; ++j)
#pragma unroll
                        for (int r = 0; r < 4; ++r) {
                            const int rl = ii * 16 + kg * 4 + r;
                            const int cl = wc * 64 + j * 16 + l15;
                            lsF[rl * 128 + cl] = acc[i][j][r];
                        }
                }
            }
            __syncthreads();
#pragma unroll
            for (int si = 0; si < 4; ++si) {
                const int row = (tid >> 5) + si * 8;
                const int colb = (tid & 31) * 4;
                float4 v = *(float4*)&lsF[row * 128 + colb];
                *(float4*)&C[(size_t)(m0 + h * 32 + row) * ldc + n0 + colb] = v;
            }
            __syncthreads();
        }
    } else {
        unsigned short* C = (unsigned short*)Cv + (size_t)b * sC;
        float evsum[4] = {0.f, 0.f, 0.f, 0.f};
#pragma unroll
        for (int i = 0; i < 4; ++i) {
#pragma unroll
            for (int r = 0; r < 4; ++r) {
                const int rowfull = wr * 64 + i * 16 + kg * 4 + r;
                uint64_t mwr = 0;
                if (MODE == M_MASK && MASKOR == 1)
                    mwr = *(const uint64_t*)&mwords[rowfull * 4 + wc * 2];
                float rs = 0.f;
#pragma unroll
                for (int j = 0; j < 4; ++j) {
                    const int cl = wc * 64 + j * 16 + l15;
                    float v = acc[i][j][r];
                    if (MODE == M_MASK) {
                        v *= scale;
                        uint32_t bit;
                        if (MASKOR == 1) {
                            bit = (uint32_t)(mwr >> (j * 16 + l15)) & 1u;
                        } else {
                            const uint64_t mwc = *(const uint64_t*)&mwords[cl * 4 + wr * 2];
                            bit = (uint32_t)(mwc >> (i * 16 + kg * 4 + r)) & 1u;
                        }
                        v = bit ? __expf(v) : 0.f;  // store exp'd score
                        if (CSUM) evsum[j] += v;
                        if (RSUM) rs += v;
                    }
                    ls[rowfull * 132 + cl] = (short)f2bf(v);
                }
                if (RSUM) {
                    rs += __shfl_xor(rs, 1, 64);
                    rs += __shfl_xor(rs, 2, 64);
                    rs += __shfl_xor(rs, 4, 64);
                    rs += __shfl_xor(rs, 8, 64);
                    if (l15 == 0)
                        atomicAdd(&sums[(size_t)b * E_ + m0 + rowfull], rs);
                }
            }
        }
        __syncthreads();
#pragma unroll
        for (int si = 0; si < 8; ++si) {
            const int row = (tid >> 4) + si * 16;
            const int col = (tid & 15) * 8;
            us8 val = *(us8*)&ls[row * 132 + col];
            *(us8*)&C[(size_t)(m0 + row) * ldc + n0 + col] = val;
        }
        if (CSUM) {
#pragma unroll
            for (int j = 0; j < 4; ++j) {
                float cs = evsum[j];
                cs += __shfl_xor(cs, 16, 64);
                cs += __shfl_xor(cs, 32, 64);
                if (kg == 0)
                    atomicAdd(&sums[(size_t)b * E_ + n0 + wc * 64 + j * 16 + l15], cs);
            }
        }
    }
}

// ---------------------------------------------------------------------------
extern "C" void kernel_launch(void* const* d_in, const int* in_sizes, int n_in,
                              void* d_out, int out_size, void* d_ws, size_t ws_size,
                              hipStream_t stream) {
    const float* hidden = (const float*)d_in[0];    // [B,N,D]
    const int* ht = (const int*)d_in[1];            // [B,E,N]
    const float* edge_emb = (const float*)d_in[2];  // [B,E,D]
    const float* wnk = (const float*)d_in[3];       // [D,D]
    const float* wek = (const float*)d_in[4];       // [D,D]
    const float* gamma = (const float*)d_in[5];     // [D]
    const float* beta = (const float*)d_in[6];      // [D]
    float* out = (float*)d_out;                     // [B,N,D]
    (void)in_sizes; (void)n_in; (void)out_size; (void)ws_size;

    char* w = (char*)d_ws;
    unsigned short* SP = (unsigned short*)w;         w += (size_t)B_ * E_ * N_ * 2;   // 134MB
    unsigned short* hidden_bf = (unsigned short*)w;  w += (size_t)B_ * N_ * D_ * 2;
    unsigned short* hiddenT_bf = (unsigned short*)w; w += (size_t)B_ * D_ * N_ * 2;
    unsigned short* node_k_bf = (unsigned short*)w;  w += (size_t)B_ * N_ * D_ * 2;
    unsigned short* eln_bf = (unsigned short*)w;     w += (size_t)B_ * E_ * D_ * 2;
    unsigned short* edge_h_bf = (unsigned short*)w;  w += (size_t)B_ * E_ * D_ * 2;
    float* ehT_f32 = (float*)w;                      w += (size_t)B_ * D_ * E_ * 4;
    unsigned short* ehsT_bf = (unsigned short*)w;    w += (size_t)B_ * D_ * E_ * 2;
    unsigned short* edge_k_bf = (unsigned short*)w;  w += (size_t)B_ * E_ * D_ * 2;
    float* slabs = (float*)w;                        w += (size_t)B_ * 2 * E_ * D_ * 4;
    uint32_t* bits = (uint32_t*)w;                   w += (size_t)B_ * E_ * (N_ / 32) * 4;
    float* rsum = (float*)w;                         w += (size_t)B_ * E_ * 4;
    float* lsum = (float*)w;                         w += (size_t)B_ * E_ * 4;
    unsigned short* wnkT = (unsigned short*)w;       w += (size_t)D_ * D_ * 2;
    unsigned short* wekT = (unsigned short*)w;       w += (size_t)D_ * D_ * 2;

    const float scale = 0.0625f;  // 1/sqrt(256)

    // prep
    prep_hidden<<<dim3(D_ / 64, N_ / 64, B_), 256, 0, stream>>>(hidden, hidden_bf, hiddenT_bf);
    cast_wT<<<D_ * D_ / 256, 256, 0, stream>>>(wnk, wnkT);
    cast_wT<<<D_ * D_ / 256, 256, 0, stream>>>(wek, wekT);
    ln_kernel<<<B_ * E_, 256, 0, stream>>>(edge_emb, gamma, beta, eln_bf);
    pack_mask<<<B_ * E_, 256, 0, stream>>>(ht, bits);
    hipMemsetAsync(rsum, 0, (size_t)B_ * E_ * 8, stream);  // rsum + lsum (adjacent)

    // node_k = hidden @ wnk
    mfma_gemm_nt<M_BF16, 0, 0, 0, 0><<<dim3(D_ / 128, (B_ * N_) / 128, 1), 256, 0, stream>>>(
        (const short*)hidden_bf, (const short*)wnkT, node_k_bf, nullptr, nullptr,
        D_, D_, 0, 0, 0, 1.f);
    // S1[e,n] = exp(mask(eln . node_k * scale)); rsum[e] = row exp-sums (RSUM)
    mfma_gemm_nt<M_MASK, 1, 1, 0, 0><<<dim3(N_ / 128, E_ / 128, B_), 256, 0, stream>>>(
        (const short*)eln_bf, (const short*)node_k_bf, SP, bits, rsum,
        D_, N_, (size_t)E_ * D_, (size_t)N_ * D_, (size_t)E_ * N_, scale);
    // PV slabs: slab[b*2+s][e,d] = sum_{n in half s} S1exp[e,n]*hidden[n,d]
    mfma_gemm_nt<M_F32, 0, 0, 1, 0><<<dim3(D_ / 128, E_ / 128, B_ * 2), 256, 0, stream>>>(
        (const short*)SP, (const short*)hiddenT_bf, slabs, nullptr, nullptr,
        N_, D_, (size_t)E_ * N_, (size_t)D_ * N_, (size_t)E_ * D_, 1.f);
    // edge_h = (slab0+slab1)/rsum + eln  -> bf16 [E,D] and f32 [D,E]
    reduce_pv<<<dim3(D_ / 64, E_ / 64, B_), 256, 0, stream>>>(
        slabs, eln_bf, rsum, edge_h_bf, ehT_f32);
    // edge_k = edge_h @ wek
    mfma_gemm_nt<M_BF16, 0, 0, 0, 0><<<dim3(D_ / 128, (B_ * E_) / 128, 1), 256, 0, stream>>>(
        (const short*)edge_h_bf, (const short*)wekT, edge_k_bf, nullptr, nullptr,
        D_, D_, 0, 0, 0, 1.f);
    // S2T[n,e] = exp(mask(node_k . edge_k * scale)); lsum[e] += col exp-sums (CSUM)
    mfma_gemm_nt<M_MASK, 2, 0, 0, 1><<<dim3(E_ / 128, N_ / 128, B_), 256, 0, stream>>>(
        (const short*)node_k_bf, (const short*)edge_k_bf, SP, bits, lsum,
        D_, E_, (size_t)N_ * D_, (size_t)E_ * D_, (size_t)N_ * E_, scale);
    // edge_hs[d,e] = ehT/lsum
    scale_ehT<<<(B_ * D_ * E_) / (256 * 8), 256, 0, stream>>>(ehT_f32, lsum, ehsT_bf);
    // out[n,d] = sum_e S2exp[n,e] * edge_hs[d,e]
    mfma_gemm_nt<M_F32, 0, 0, 0, 0><<<dim3(D_ / 128, N_ / 128, B_), 256, 0, stream>>>(
        (const short*)SP, (const short*)ehsT_bf, out, nullptr, nullptr,
        E_, D_, (size_t)N_ * E_, (size_t)D_ * E_, (size_t)N_ * D_, 1.f);
}

// Round 10
// 720.412 us; speedup vs baseline: 1.1949x; 1.0427x over previous
//
#include <hip/hip_runtime.h>
#include <hip/hip_bf16.h>
#include <stdint.h>

// R16: R15 (751 µs) + certain-small-win bundle:
//  - ehT stored bf16 instead of f32 (saves ~100 MB round trip; one extra
//    bf16 rounding of edge_h before /lsum, same rounding class as edge_h_bf)
//  - ln_kernel + pack_mask merged (same grid, row-aligned; one launch less)
//  - both cast_wT launches merged into one kernel
// GEMM structure, tiles, and all numerics of the verified pipeline unchanged.

#define B_ 8
#define N_ 4096
#define E_ 2048
#define D_ 256
#define INF_SUB (-9.0e15f)

typedef short bf16x8 __attribute__((ext_vector_type(8)));
typedef float f32x4 __attribute__((ext_vector_type(4)));
typedef unsigned short us8 __attribute__((ext_vector_type(8)));

#define AS1 __attribute__((address_space(1)))
#define AS3 __attribute__((address_space(3)))

__device__ __forceinline__ unsigned short f2bf(float f) {
    union { float f; unsigned int u; } v; v.f = f;
    unsigned int r = v.u + 0x7fffu + ((v.u >> 16) & 1u);
    return (unsigned short)(r >> 16);
}
__device__ __forceinline__ float bf2f(unsigned short h) {
    union { unsigned int u; float f; } v; v.u = ((unsigned int)h) << 16;
    return v.f;
}
__device__ __forceinline__ float waveReduceSum(float v) {
#pragma unroll
    for (int o = 32; o > 0; o >>= 1) v += __shfl_xor(v, o, 64);
    return v;
}

// -------- merged: LayerNorm(edge_emb row) + pack(ht row) --------------------
// grid = B*E blocks; row index is shared by both ops.
__global__ __launch_bounds__(256) void ln_pack(const float* __restrict__ x,
                                               const float* __restrict__ gamma,
                                               const float* __restrict__ beta,
                                               unsigned short* __restrict__ yb,
                                               const int* __restrict__ ht,
                                               uint32_t* __restrict__ bits) {
    __shared__ float red[8];
    __shared__ __align__(8) unsigned char nib[256];
    const int row = blockIdx.x;
    const int t = threadIdx.x;
    const int lane = t & 63, wid = t >> 6;

    // ---- pack ht row (int4 loads + nibble compaction) ----
    const int* hrow = ht + (size_t)row * N_;
    uint32_t* brow = bits + (size_t)row * (N_ / 32);
    // ---- LN load (overlaps with pack loads) ----
    const float v = x[(size_t)row * D_ + t];

#pragma unroll
    for (int it = 0; it < 4; ++it) {
        const int4 hv = *(const int4*)&hrow[it * 1024 + t * 4];
        unsigned char n = (unsigned char)((hv.x > 0) | ((hv.y > 0) << 1) |
                                          ((hv.z > 0) << 2) | ((hv.w > 0) << 3));
        nib[t] = n;
        __syncthreads();
        if (t < 32) {
            uint64_t xx = *(const uint64_t*)&nib[t * 8];
            xx = (xx | (xx >> 4)) & 0x00FF00FF00FF00FFull;
            xx = (xx | (xx >> 8)) & 0x0000FFFF0000FFFFull;
            brow[it * 32 + t] = (uint32_t)(xx | (xx >> 16));
        }
        __syncthreads();
    }

    // ---- LN compute ----
    float s = waveReduceSum(v);
    if (lane == 0) red[wid] = s;
    __syncthreads();
    const float mu = (red[0] + red[1] + red[2] + red[3]) * (1.0f / D_);
    const float d = v - mu;
    float s2 = waveReduceSum(d * d);
    if (lane == 0) red[4 + wid] = s2;
    __syncthreads();
    const float var = (red[4] + red[5] + red[6] + red[7]) * (1.0f / D_);
    yb[(size_t)row * D_ + t] = f2bf(gamma[t] * d * rsqrtf(var + 1e-5f) + beta[t]);
}

// ---------------- fp32 [N,D] -> bf16 [N,D] + bf16 [D,N] ---------------------
__global__ __launch_bounds__(256) void prep_hidden(const float* __restrict__ in,
                                                   unsigned short* __restrict__ hb,
                                                   unsigned short* __restrict__ hT) {
    __shared__ unsigned short tile[64][65];
    const int b = blockIdx.z;
    in += (size_t)b * N_ * D_;
    hb += (size_t)b * N_ * D_;
    hT += (size_t)b * D_ * N_;
    const int n0 = blockIdx.y * 64, d0 = blockIdx.x * 64;
    const int t = threadIdx.x;
    const int tr = t >> 4, tc = (t & 15) * 4;
#pragma unroll
    for (int q = 0; q < 4; ++q) {
        const int rr = q * 16 + tr;
        const float4 f = *(const float4*)&in[(size_t)(n0 + rr) * D_ + d0 + tc];
        unsigned short h0 = f2bf(f.x), h1 = f2bf(f.y), h2 = f2bf(f.z), h3 = f2bf(f.w);
        *(ushort4*)&hb[(size_t)(n0 + rr) * D_ + d0 + tc] = make_ushort4(h0, h1, h2, h3);
        tile[rr][tc + 0] = h0; tile[rr][tc + 1] = h1;
        tile[rr][tc + 2] = h2; tile[rr][tc + 3] = h3;
    }
    __syncthreads();
#pragma unroll
    for (int q = 0; q < 4; ++q) {
        const int cc = q * 16 + tr;
        ushort4 o = make_ushort4(tile[tc + 0][cc], tile[tc + 1][cc],
                                 tile[tc + 2][cc], tile[tc + 3][cc]);
        *(ushort4*)&hT[(size_t)(d0 + cc) * N_ + n0 + tc] = o;
    }
}

// -------- tiny: both weights [D,D] f32 -> [D,D] bf16 transposed -------------
__global__ __launch_bounds__(256) void cast_wT2(const float* __restrict__ w1,
                                                unsigned short* __restrict__ w1T,
                                                const float* __restrict__ w2,
                                                unsigned short* __restrict__ w2T) {
    const int gid = blockIdx.x * 256 + threadIdx.x;
    const int which = gid >> 16;  // 65536 elements per matrix
    const int e = gid & 0xFFFF;
    const int i = e >> 8, j = e & 255;
    if (which == 0) w1T[j * D_ + i] = f2bf(w1[i * D_ + j]);
    else            w2T[j * D_ + i] = f2bf(w2[i * D_ + j]);
}

// ---- PV slab reduce: edge_h = (slab0+slab1)/rsum + eln; bf16 [E,D]+[D,E] ---
__global__ __launch_bounds__(256) void reduce_pv(const float* __restrict__ slab,
                                                 const unsigned short* __restrict__ eln,
                                                 const float* __restrict__ rsum,
                                                 unsigned short* __restrict__ eh,
                                                 unsigned short* __restrict__ ehT) {
    __shared__ float tile[64][65];
    const int b = blockIdx.z;
    const float* s0 = slab + (size_t)(b * 2) * E_ * D_;
    const float* s1 = slab + (size_t)(b * 2 + 1) * E_ * D_;
    const int e0 = blockIdx.y * 64, d0 = blockIdx.x * 64;
    const int t = threadIdx.x;
    const int tr = t >> 4, tc = (t & 15) * 4;
#pragma unroll
    for (int q = 0; q < 4; ++q) {
        const int rr = q * 16 + tr;
        const int row = e0 + rr;
        const float4 v0 = *(const float4*)&s0[(size_t)row * D_ + d0 + tc];
        const float4 v1 = *(const float4*)&s1[(size_t)row * D_ + d0 + tc];
        const float inv = 1.0f / rsum[(size_t)b * E_ + row];
        const ushort4 el = *(const ushort4*)&eln[(size_t)b * E_ * D_ + (size_t)row * D_ + d0 + tc];
        const float x0 = (v0.x + v1.x) * inv + bf2f(el.x);
        const float x1 = (v0.y + v1.y) * inv + bf2f(el.y);
        const float x2 = (v0.z + v1.z) * inv + bf2f(el.z);
        const float x3 = (v0.w + v1.w) * inv + bf2f(el.w);
        *(ushort4*)&eh[(size_t)b * E_ * D_ + (size_t)row * D_ + d0 + tc] =
            make_ushort4(f2bf(x0), f2bf(x1), f2bf(x2), f2bf(x3));
        tile[rr][tc + 0] = x0; tile[rr][tc + 1] = x1;
        tile[rr][tc + 2] = x2; tile[rr][tc + 3] = x3;
    }
    __syncthreads();
#pragma unroll
    for (int q = 0; q < 4; ++q) {
        const int cc = q * 16 + tr;
        ushort4 o = make_ushort4(f2bf(tile[tc + 0][cc]), f2bf(tile[tc + 1][cc]),
                                 f2bf(tile[tc + 2][cc]), f2bf(tile[tc + 3][cc]));
        *(ushort4*)&ehT[(size_t)b * D_ * E_ + (size_t)(d0 + cc) * E_ + e0 + tc] = o;
    }
}

// ---- edge_hsT[d,e] = ehT[d,e] / lsum[e]  (bf16 in, bf16 out, [B,D,E]) ------
__global__ __launch_bounds__(256) void scale_ehT(const unsigned short* __restrict__ ehT,
                                                 const float* __restrict__ lsum,
                                                 unsigned short* __restrict__ ehs) {
    const size_t base = ((size_t)blockIdx.x * 256 + threadIdx.x) * 8;
    const int b = (int)(base / ((size_t)D_ * E_));
    const int e = (int)(base % E_);
    const us8 f = *(const us8*)&ehT[base];
    const float4 l0 = *(const float4*)&lsum[(size_t)b * E_ + e];
    const float4 l1 = *(const float4*)&lsum[(size_t)b * E_ + e + 4];
    us8 o;
    o[0] = f2bf(bf2f(f[0]) / l0.x); o[1] = f2bf(bf2f(f[1]) / l0.y);
    o[2] = f2bf(bf2f(f[2]) / l0.z); o[3] = f2bf(bf2f(f[3]) / l0.w);
    o[4] = f2bf(bf2f(f[4]) / l1.x); o[5] = f2bf(bf2f(f[5]) / l1.y);
    o[6] = f2bf(bf2f(f[6]) / l1.z); o[7] = f2bf(bf2f(f[7]) / l1.w);
    *(us8*)&ehs[base] = o;
}

// ---------------- MFMA NT GEMM: C[m,n] = sum_k A[m,k]*Bt[n,k] ---------------
// 128x128 tile, BK=64, global_load_lds w=16, chunk-rotate swizzle mod 8.
// M_MASK stores bf16(exp(masked v)) (masked -> 0.0). RSUM: row exp-sums.
// CSUM: column exp-sums.
#define M_BF16 0
#define M_MASK 1
#define M_F32 2

template <int MODE, int MASKOR, int RSUM, int SPLIT, int CSUM>
__global__ __launch_bounds__(256) void mfma_gemm_nt(
        const short* __restrict__ A, const short* __restrict__ Bm,
        void* __restrict__ Cv, const uint32_t* __restrict__ bits,
        float* __restrict__ sums,
        int K, int ldc, size_t sA, size_t sB, size_t sC, float scale) {
    __shared__ __align__(16) short ls[(MODE == M_F32) ? 16384 : 16896];
    __shared__ uint32_t mwords[MASKOR ? 512 : 4];
    short* lsA = ls;              // 128 x 64 bf16 = 16 KB
    short* lsB = ls + 8192;       // 128 x 64 bf16 = 16 KB
    const int zb = blockIdx.z;
    const int b = SPLIT ? (zb >> 1) : zb;
    A += (size_t)b * sA;
    Bm += (size_t)b * sB;
    const int m0 = blockIdx.y * 128, n0 = blockIdx.x * 128;
    const int tid = threadIdx.x, wid = tid >> 6, lane = tid & 63;
    const int l15 = lane & 15, kg = lane >> 4;
    const int wr = wid >> 1, wc = wid & 1;

    if (MASKOR) {
        const uint32_t* bb = bits + (size_t)b * E_ * (N_ / 32);
#pragma unroll
        for (int q = 0; q < 2; ++q) {
            const int idx = q * 256 + tid;
            mwords[idx] = (MASKOR == 1)
                ? bb[(size_t)(m0 + (idx >> 2)) * (N_ / 32) + (n0 >> 5) + (idx & 3)]
                : bb[(size_t)(n0 + (idx >> 2)) * (N_ / 32) + (m0 >> 5) + (idx & 3)];
        }
    }

    int raoff[4], rota[4], rboff[4], rotb[4];
#pragma unroll
    for (int i = 0; i < 4; ++i) {
        const int ra = wr * 64 + i * 16 + l15;
        raoff[i] = ra * 64; rota[i] = kg + (ra >> 1);
        const int rb = wc * 64 + i * 16 + l15;
        rboff[i] = rb * 64; rotb[i] = kg + (rb >> 1);
    }
    const f32x4 zero = {0.f, 0.f, 0.f, 0.f};
    f32x4 acc[4][4];
#pragma unroll
    for (int i = 0; i < 4; ++i)
#pragma unroll
        for (int j = 0; j < 4; ++j) acc[i][j] = zero;

    const int kt0 = SPLIT ? (zb & 1) * (K >> 1) : 0;
    const int ktE = SPLIT ? kt0 + (K >> 1) : K;
    for (int kt = kt0; kt < ktE; kt += 64) {
        __syncthreads();
#pragma unroll
        for (int q = 0; q < 4; ++q) {
            const int c = q * 256 + tid;
            const int r = c >> 3;
            const int kc = ((c & 7) - (r >> 1)) & 7;
            const short* ga = A + (size_t)(m0 + r) * K + kt + kc * 8;
            __builtin_amdgcn_global_load_lds((const AS1 void*)ga,
                (AS3 void*)(lsA + (q * 256 + wid * 64) * 8), 16, 0, 0);
            const short* gb = Bm + (size_t)(n0 + r) * K + kt + kc * 8;
            __builtin_amdgcn_global_load_lds((const AS1 void*)gb,
                (AS3 void*)(lsB + (q * 256 + wid * 64) * 8), 16, 0, 0);
        }
        __syncthreads();
#pragma unroll
        for (int s = 0; s < 2; ++s) {
            bf16x8 fa[4], fb[4];
#pragma unroll
            for (int i = 0; i < 4; ++i)
                fa[i] = *(const bf16x8*)(lsA + raoff[i] + (((s * 4 + rota[i]) & 7) << 3));
#pragma unroll
            for (int j = 0; j < 4; ++j)
                fb[j] = *(const bf16x8*)(lsB + rboff[j] + (((s * 4 + rotb[j]) & 7) << 3));
#pragma unroll
            for (int i = 0; i < 4; ++i)
#pragma unroll
                for (int j = 0; j < 4; ++j)
                    acc[i][j] = __builtin_amdgcn_mfma_f32_16x16x32_bf16(fa[i], fb[j], acc[i][j], 0, 0, 0);
        }
    }

    __syncthreads();  // fragment reads done; ls free for repack

    if (MODE == M_F32) {
        float* C = (float*)Cv + (SPLIT ? (size_t)zb * sC : (size_t)b * sC);
        float* lsF = (float*)ls;
#pragma unroll
        for (int h = 0; h < 4; ++h) {
            if (wr == (h >> 1)) {
#pragma unroll
                for (int ii = 0; ii < 2; ++ii) {
                    const int i = (h & 1) * 2 + ii;
#pragma unroll
                    for (int j = 0; j < 4; ++j)
#pragma unroll
                        for (int r = 0; r < 4; ++r) {
                            const int rl = ii * 16 + kg * 4 + r;
                            const int cl = wc * 64 + j * 16 + l15;
                            lsF[rl * 128 + cl] = acc[i][j][r];
                        }
                }
            }
            __syncthreads();
#pragma unroll
            for (int si = 0; si < 4; ++si) {
                const int row = (tid >> 5) + si * 8;
                const int colb = (tid & 31) * 4;
                float4 v = *(float4*)&lsF[row * 128 + colb];
                *(float4*)&C[(size_t)(m0 + h * 32 + row) * ldc + n0 + colb] = v;
            }
            __syncthreads();
        }
    } else {
        unsigned short* C = (unsigned short*)Cv + (size_t)b * sC;
        float evsum[4] = {0.f, 0.f, 0.f, 0.f};
#pragma unroll
        for (int i = 0; i < 4; ++i) {
#pragma unroll
            for (int r = 0; r < 4; ++r) {
                const int rowfull = wr * 64 + i * 16 + kg * 4 + r;
                uint64_t mwr = 0;
                if (MODE == M_MASK && MASKOR == 1)
                    mwr = *(const uint64_t*)&mwords[rowfull * 4 + wc * 2];
                float rs = 0.f;
#pragma unroll
                for (int j = 0; j < 4; ++j) {
                    const int cl = wc * 64 + j * 16 + l15;
                    float v = acc[i][j][r];
                    if (MODE == M_MASK) {
                        v *= scale;
                        uint32_t bit;
                        if (MASKOR == 1) {
                            bit = (uint32_t)(mwr >> (j * 16 + l15)) & 1u;
                        } else {
                            const uint64_t mwc = *(const uint64_t*)&mwords[cl * 4 + wr * 2];
                            bit = (uint32_t)(mwc >> (i * 16 + kg * 4 + r)) & 1u;
                        }
                        v = bit ? __expf(v) : 0.f;  // store exp'd score
                        if (CSUM) evsum[j] += v;
                        if (RSUM) rs += v;
                    }
                    ls[rowfull * 132 + cl] = (short)f2bf(v);
                }
                if (RSUM) {
                    rs += __shfl_xor(rs, 1, 64);
                    rs += __shfl_xor(rs, 2, 64);
                    rs += __shfl_xor(rs, 4, 64);
                    rs += __shfl_xor(rs, 8, 64);
                    if (l15 == 0)
                        atomicAdd(&sums[(size_t)b * E_ + m0 + rowfull], rs);
                }
            }
        }
        __syncthreads();
#pragma unroll
        for (int si = 0; si < 8; ++si) {
            const int row = (tid >> 4) + si * 16;
            const int col = (tid & 15) * 8;
            us8 val = *(us8*)&ls[row * 132 + col];
            *(us8*)&C[(size_t)(m0 + row) * ldc + n0 + col] = val;
        }
        if (CSUM) {
#pragma unroll
            for (int j = 0; j < 4; ++j) {
                float cs = evsum[j];
                cs += __shfl_xor(cs, 16, 64);
                cs += __shfl_xor(cs, 32, 64);
                if (kg == 0)
                    atomicAdd(&sums[(size_t)b * E_ + n0 + wc * 64 + j * 16 + l15], cs);
            }
        }
    }
}

// ---------------------------------------------------------------------------
extern "C" void kernel_launch(void* const* d_in, const int* in_sizes, int n_in,
                              void* d_out, int out_size, void* d_ws, size_t ws_size,
                              hipStream_t stream) {
    const float* hidden = (const float*)d_in[0];    // [B,N,D]
    const int* ht = (const int*)d_in[1];            // [B,E,N]
    const float* edge_emb = (const float*)d_in[2];  // [B,E,D]
    const float* wnk = (const float*)d_in[3];       // [D,D]
    const float* wek = (const float*)d_in[4];       // [D,D]
    const float* gamma = (const float*)d_in[5];     // [D]
    const float* beta = (const float*)d_in[6];      // [D]
    float* out = (float*)d_out;                     // [B,N,D]
    (void)in_sizes; (void)n_in; (void)out_size; (void)ws_size;

    char* w = (char*)d_ws;
    unsigned short* SP = (unsigned short*)w;         w += (size_t)B_ * E_ * N_ * 2;   // 134MB
    unsigned short* hidden_bf = (unsigned short*)w;  w += (size_t)B_ * N_ * D_ * 2;
    unsigned short* hiddenT_bf = (unsigned short*)w; w += (size_t)B_ * D_ * N_ * 2;
    unsigned short* node_k_bf = (unsigned short*)w;  w += (size_t)B_ * N_ * D_ * 2;
    unsigned short* eln_bf = (unsigned short*)w;     w += (size_t)B_ * E_ * D_ * 2;
    unsigned short* edge_h_bf = (unsigned short*)w;  w += (size_t)B_ * E_ * D_ * 2;
    unsigned short* ehT_bf = (unsigned short*)w;     w += (size_t)B_ * D_ * E_ * 2;
    unsigned short* ehsT_bf = (unsigned short*)w;    w += (size_t)B_ * D_ * E_ * 2;
    unsigned short* edge_k_bf = (unsigned short*)w;  w += (size_t)B_ * E_ * D_ * 2;
    float* slabs = (float*)w;                        w += (size_t)B_ * 2 * E_ * D_ * 4;
    uint32_t* bits = (uint32_t*)w;                   w += (size_t)B_ * E_ * (N_ / 32) * 4;
    float* rsum = (float*)w;                         w += (size_t)B_ * E_ * 4;
    float* lsum = (float*)w;                         w += (size_t)B_ * E_ * 4;
    unsigned short* wnkT = (unsigned short*)w;       w += (size_t)D_ * D_ * 2;
    unsigned short* wekT = (unsigned short*)w;       w += (size_t)D_ * D_ * 2;

    const float scale = 0.0625f;  // 1/sqrt(256)

    // prep
    prep_hidden<<<dim3(D_ / 64, N_ / 64, B_), 256, 0, stream>>>(hidden, hidden_bf, hiddenT_bf);
    cast_wT2<<<2 * D_ * D_ / 256, 256, 0, stream>>>(wnk, wnkT, wek, wekT);
    ln_pack<<<B_ * E_, 256, 0, stream>>>(edge_emb, gamma, beta, eln_bf, ht, bits);
    hipMemsetAsync(rsum, 0, (size_t)B_ * E_ * 8, stream);  // rsum + lsum (adjacent)

    // node_k = hidden @ wnk
    mfma_gemm_nt<M_BF16, 0, 0, 0, 0><<<dim3(D_ / 128, (B_ * N_) / 128, 1), 256, 0, stream>>>(
        (const short*)hidden_bf, (const short*)wnkT, node_k_bf, nullptr, nullptr,
        D_, D_, 0, 0, 0, 1.f);
    // S1[e,n] = exp(mask(eln . node_k * scale)); rsum[e] = row exp-sums (RSUM)
    mfma_gemm_nt<M_MASK, 1, 1, 0, 0><<<dim3(N_ / 128, E_ / 128, B_), 256, 0, stream>>>(
        (const short*)eln_bf, (const short*)node_k_bf, SP, bits, rsum,
        D_, N_, (size_t)E_ * D_, (size_t)N_ * D_, (size_t)E_ * N_, scale);
    // PV slabs: slab[b*2+s][e,d] = sum_{n in half s} S1exp[e,n]*hidden[n,d]
    mfma_gemm_nt<M_F32, 0, 0, 1, 0><<<dim3(D_ / 128, E_ / 128, B_ * 2), 256, 0, stream>>>(
        (const short*)SP, (const short*)hiddenT_bf, slabs, nullptr, nullptr,
        N_, D_, (size_t)E_ * N_, (size_t)D_ * N_, (size_t)E_ * D_, 1.f);
    // edge_h = (slab0+slab1)/rsum + eln  -> bf16 [E,D] and bf16 [D,E]
    reduce_pv<<<dim3(D_ / 64, E_ / 64, B_), 256, 0, stream>>>(
        slabs, eln_bf, rsum, edge_h_bf, ehT_bf);
    // edge_k = edge_h @ wek
    mfma_gemm_nt<M_BF16, 0, 0, 0, 0><<<dim3(D_ / 128, (B_ * E_) / 128, 1), 256, 0, stream>>>(
        (const short*)edge_h_bf, (const short*)wekT, edge_k_bf, nullptr, nullptr,
        D_, D_, 0, 0, 0, 1.f);
    // S2T[n,e] = exp(mask(node_k . edge_k * scale)); lsum[e] += col exp-sums (CSUM)
    mfma_gemm_nt<M_MASK, 2, 0, 0, 1><<<dim3(E_ / 128, N_ / 128, B_), 256, 0, stream>>>(
        (const short*)node_k_bf, (const short*)edge_k_bf, SP, bits, lsum,
        D_, E_, (size_t)N_ * D_, (size_t)E_ * D_, (size_t)N_ * E_, scale);
    // edge_hs[d,e] = ehT/lsum
    scale_ehT<<<(B_ * D_ * E_) / (256 * 8), 256, 0, stream>>>(ehT_bf, lsum, ehsT_bf);
    // out[n,d] = sum_e S2exp[n,e] * edge_hs[d,e]
    mfma_gemm_nt<M_F32, 0, 0, 0, 0><<<dim3(D_ / 128, N_ / 128, B_), 256, 0, stream>>>(
        (const short*)SP, (const short*)ehsT_bf, out, nullptr, nullptr,
        E_, D_, (size_t)N_ * E_, (size_t)D_ * E_, (size_t)N_ * D_, 1.f);
}